// Round 15
// baseline (68.382 us; speedup 1.0000x reference)
//
#include <hip/hip_runtime.h>
#include <math.h>

// TopKGate: logits = x @ W^T ; softmax ; top-2 ; scatter weights + indices(float).
// x: [8192,4096] f32, W: [64,4096] f32.
// d_out (f32 flat): weights [8192*64] then indices [8192*2] as floats.
//
// MFMA path: f32 as bf16 hi/lo split, 3 passes (hh+lh+hl; ll ~2^-16 dropped).
// Round-15 (round-13 base; round-14's 32x32 regressed -> reverted):
//  - 1024-thr blocks: 16 waves x 16 tokens = 256 tok/block; grid = 32 tg x
//    8 ks = 256 blocks = ONE round at 1 block/CU, 16 waves/CU (round-13 ran
//    two rounds at 8 waves/CU). blockIdx%8 = ks -> same-B blocks share XCD.
//  - prepw fused in: each block builds its own B panel straight from W
//    (128 KB f32 slice, L2-hot) with the validated prepw mapping; kills one
//    launch + the Whf/Wlf global round-trip.
//  - Per-wave loop, x ring depth 6, SBAR phases, partials, finalize: unchanged.

#define TOKENS 8192
#define DIM    4096
#define NEXP   64

#define KS     8                             // k-split across blocks
#define KSEG   (DIM / KS)                    // 512 k per block
#define NCH    (KSEG / 32)                   // 16 chunks per block

#define SBAR() __builtin_amdgcn_sched_barrier(0)

typedef __attribute__((ext_vector_type(8))) short  short8;
typedef __attribute__((ext_vector_type(4))) float  f32x4;
typedef __attribute__((ext_vector_type(8))) float  f32x8;

__device__ __forceinline__ void bf16split(float v, short& hi, short& lo) {
    unsigned u = __float_as_uint(v);
    hi = (short)(u >> 16);
    float r = v - __uint_as_float(u & 0xffff0000u);
    lo = (short)(__float_as_uint(r) >> 16);
}

// ---- main: 256 tokens/block (16 waves x 16), B panel built in-kernel ----
__global__ __launch_bounds__(1024, 4)
void tg_mfma(const float* __restrict__ x, const float* __restrict__ W,
             float* __restrict__ part) {
    // B panel: [hi/lo][chunk][nt][lane] short8 = 128 KB
    __shared__ short8 Bls[2][NCH][4][64];

    const int tid  = threadIdx.x;
    const int lane = tid & 63;
    const int wave = tid >> 6;                   // token sub-group 0..15
    const int tg   = blockIdx.x >> 3;            // token group 0..31
    const int ks   = blockIdx.x & 7;             // k split 0..7
    const int t0   = tg * 256 + wave * 16;
    const int row  = lane & 15;                  // A row (token) / D col tag
    const int grp  = lane >> 4;

    // ---- in-kernel B prep: same mapping as the validated tg_prepw ----
    // slot s -> c = s>>8, nt = (s&255)>>6, ln = s&63;
    // e = nt*16+(ln&15), k = ks*KSEG + c*32 + (ln>>4)*8
#pragma unroll
    for (int s4 = 0; s4 < 4; ++s4) {
        const int s   = s4 * 1024 + tid;
        const int c   = s >> 8;
        const int rem = s & 255;
        const int nt  = rem >> 6;
        const int ln  = rem & 63;
        const int e   = nt * 16 + (ln & 15);
        const int kb  = ks * KSEG + c * 32 + (ln >> 4) * 8;
        const f32x8 wv = *reinterpret_cast<const f32x8*>(W + (size_t)e * DIM + kb);
        short8 h, l;
#pragma unroll
        for (int j = 0; j < 8; ++j) {
            short hh, ll;
            bf16split(wv[j], hh, ll);
            h[j] = hh; l[j] = ll;
        }
        Bls[0][c][nt][ln] = h;
        Bls[1][c][nt][ln] = l;
    }
    __syncthreads();   // the only barrier in the kernel

    const float* xp = x + (size_t)(t0 + row) * DIM + ks * KSEG + grp * 8;

    f32x4 acc[4];
#pragma unroll
    for (int nt = 0; nt < 4; ++nt) acc[nt] = (f32x4){0.f, 0.f, 0.f, 0.f};

    short8 bA[8], bB[8];
    auto dsB = [&](short8 (&b)[8], int c) {      // 8 x ds_read_b128, conflict-free
#pragma unroll
        for (int nt = 0; nt < 4; ++nt) {
            b[nt]     = Bls[0][c][nt][lane];
            b[4 + nt] = Bls[1][c][nt][lane];
        }
    };
    auto ldx = [&](int c) {
        return *reinterpret_cast<const f32x8*>(xp + c * 32);
    };
    auto cvt = [&](const f32x8& xv, short8& ah, short8& al) {
#pragma unroll
        for (int j = 0; j < 8; ++j) {
            short hh, ll;
            bf16split(xv[j], hh, ll);
            ah[j] = hh; al[j] = ll;
        }
    };
    auto mfma12 = [&](const short8& ah, const short8& al, const short8 (&b)[8]) {
        // 3-pass split: hh + lh + hl (ll ~ 2^-16 relative, dropped)
#pragma unroll
        for (int nt = 0; nt < 4; ++nt)
            acc[nt] = __builtin_amdgcn_mfma_f32_16x16x32_bf16(ah, b[nt], acc[nt], 0, 0, 0);
#pragma unroll
        for (int nt = 0; nt < 4; ++nt)
            acc[nt] = __builtin_amdgcn_mfma_f32_16x16x32_bf16(al, b[nt], acc[nt], 0, 0, 0);
#pragma unroll
        for (int nt = 0; nt < 4; ++nt)
            acc[nt] = __builtin_amdgcn_mfma_f32_16x16x32_bf16(ah, b[4 + nt], acc[nt], 0, 0, 0);
    };

    // prologue: B(0) from LDS, x ring depth 6 in flight
    f32x8 x0 = ldx(0), x1 = ldx(1), x2 = ldx(2),
          x3 = ldx(3), x4 = ldx(4), x5 = ldx(5);
    dsB(bA, 0);
    SBAR();

    short8 ah, al;
#define PH(c, XV, BC, BN)                                            \
    {                                                                \
        cvt(XV, ah, al);          /* convert frees XV's slot */      \
        SBAR();                                                      \
        if ((c) + 1 < NCH) dsB(BN, (c) + 1);                         \
        if ((c) + 6 < NCH) XV = ldx((c) + 6);                        \
        SBAR();                                                      \
        mfma12(ah, al, BC);                                          \
        SBAR();                                                      \
    }

    PH(0,  x0, bA, bB)
    PH(1,  x1, bB, bA)
    PH(2,  x2, bA, bB)
    PH(3,  x3, bB, bA)
    PH(4,  x4, bA, bB)
    PH(5,  x5, bB, bA)
    PH(6,  x0, bA, bB)
    PH(7,  x1, bB, bA)
    PH(8,  x2, bA, bB)
    PH(9,  x3, bB, bA)
    PH(10, x4, bA, bB)
    PH(11, x5, bB, bA)
    PH(12, x0, bA, bB)
    PH(13, x1, bB, bA)
    PH(14, x2, bA, bB)
    PH(15, x3, bB, bA)
#undef PH

    // ---- direct partial write: wave owns its 16 tokens, no reduction ----
    // D layout (m89-verified): col = lane&15, row = grp*4 + reg
    float* pp = part + ((size_t)ks * TOKENS + t0) * NEXP;
#pragma unroll
    for (int nt = 0; nt < 4; ++nt)
#pragma unroll
        for (int r = 0; r < 4; ++r)
            pp[(grp * 4 + r) * NEXP + nt * 16 + row] = acc[nt][r];
}

// ---- finalize: sum 8 k-split partials, wave-per-token softmax + top-2 ----
__global__ __launch_bounds__(256)
void tg_final(const float* __restrict__ part,
              float* __restrict__ out_w, float* __restrict__ out_i) {
    const int lane = threadIdx.x & 63;
    const int wv   = threadIdx.x >> 6;
    const int t    = blockIdx.x * 4 + wv;        // one token per wave

    float s = 0.0f;
#pragma unroll
    for (int k = 0; k < KS; ++k)                 // coalesced 256-B reads
        s += part[((size_t)k * TOKENS + t) * NEXP + lane];

    // softmax over 64 lanes (butterfly: all lanes converge bit-identically)
    float m = s;
#pragma unroll
    for (int o = 32; o > 0; o >>= 1) m = fmaxf(m, __shfl_xor(m, o));
    float p = expf(s - m);
    float sum = p;
#pragma unroll
    for (int o = 32; o > 0; o >>= 1) sum += __shfl_xor(sum, o);
    const float prob = p / sum;

    // top-1: max value, tie -> lower index (jax top_k order)
    float v1 = prob; int i1 = lane;
#pragma unroll
    for (int o = 32; o > 0; o >>= 1) {
        float ov = __shfl_xor(v1, o); int oi = __shfl_xor(i1, o);
        if (ov > v1 || (ov == v1 && oi < i1)) { v1 = ov; i1 = oi; }
    }
    // top-2: mask winner (probs >= 0 > -1)
    float v2 = (lane == i1) ? -1.0f : prob; int i2 = lane;
#pragma unroll
    for (int o = 32; o > 0; o >>= 1) {
        float ov = __shfl_xor(v2, o); int oi = __shfl_xor(i2, o);
        if (ov > v2 || (ov == v2 && oi < i2)) { v2 = ov; i2 = oi; }
    }

    out_w[(size_t)t * NEXP + lane] = (lane == i1) ? v1 : (lane == i2) ? v2 : 0.0f;
    if (lane == 0) {
        out_i[(size_t)t * 2 + 0] = (float)i1;
        out_i[(size_t)t * 2 + 1] = (float)i2;
    }
}

extern "C" void kernel_launch(void* const* d_in, const int* in_sizes, int n_in,
                              void* d_out, int out_size, void* d_ws, size_t ws_size,
                              hipStream_t stream) {
    const float* x = (const float*)d_in[0];
    const float* W = (const float*)d_in[1];
    float* out_w = (float*)d_out;
    float* out_i = out_w + (size_t)TOKENS * NEXP;

    float* part = (float*)d_ws;   // KS * 8192 * 64 f32 = 16 MB

    tg_mfma <<<dim3((TOKENS / 256) * KS), dim3(1024), 0, stream>>>(x, W, part);
    tg_final<<<dim3(TOKENS / 4), dim3(256), 0, stream>>>(part, out_w, out_i);
}

// Round 16
// 43.827 us; speedup vs baseline: 1.5603x; 1.5603x over previous
//
#include <hip/hip_runtime.h>
#include <math.h>

// TopKGate: logits = x @ W^T ; softmax ; top-2 ; scatter weights + indices(float).
// x: [8192,4096] f32, W: [64,4096] f32.
// d_out (f32 flat): weights [8192*64] then indices [8192*2] as floats.
//
// MFMA path: f32 as bf16 hi/lo split, 3 passes (hh+lh+hl; ll ~2^-16 dropped).
// Round-16 = round-13 geometry (512 thr, launch_bounds(512,2) -> 256-VGPR
// class; R15's 1024-thr block capped VGPR at 128 and spilled 121 MB scratch)
// + R15's validated in-kernel B prep (kills prepw launch + 1 MB round-trip)
// + s_setprio(1) around the MFMA cluster (independent-wave structure, T5).
// 8 waves x 16 tok = 128 tok/block; grid = 64 tg x 8 ks = 512 blocks;
// B panel K=512 (128 KB LDS) staged once, one barrier; x-only vmem stream,
// ring depth 6; B ds_read ping-pong; partials + KS=8 wave-per-token finalize.

#define TOKENS 8192
#define DIM    4096
#define NEXP   64

#define KS     8                             // k-split across blocks
#define KSEG   (DIM / KS)                    // 512 k per block
#define NCH    (KSEG / 32)                   // 16 chunks per block

#define SBAR() __builtin_amdgcn_sched_barrier(0)

typedef __attribute__((ext_vector_type(8))) short  short8;
typedef __attribute__((ext_vector_type(4))) float  f32x4;
typedef __attribute__((ext_vector_type(8))) float  f32x8;

__device__ __forceinline__ void bf16split(float v, short& hi, short& lo) {
    unsigned u = __float_as_uint(v);
    hi = (short)(u >> 16);
    float r = v - __uint_as_float(u & 0xffff0000u);
    lo = (short)(__float_as_uint(r) >> 16);
}

// ---- main: 128 tokens/block (8 waves x 16), B panel built in-kernel ----
__global__ __launch_bounds__(512, 2)
void tg_mfma(const float* __restrict__ x, const float* __restrict__ W,
             float* __restrict__ part) {
    // B panel: [hi/lo][chunk][nt][lane] short8 = 128 KB
    __shared__ short8 Bls[2][NCH][4][64];

    const int tid  = threadIdx.x;
    const int lane = tid & 63;
    const int wave = tid >> 6;                   // token sub-group 0..7
    const int tg   = blockIdx.x >> 3;            // token group 0..63
    const int ks   = blockIdx.x & 7;             // k split 0..7
    const int t0   = tg * 128 + wave * 16;
    const int row  = lane & 15;                  // A row (token) / D col tag
    const int grp  = lane >> 4;

    // ---- in-kernel B prep (validated in R15): slot s -> c,nt,ln ----
    // e = nt*16+(ln&15), k = ks*KSEG + c*32 + (ln>>4)*8
#pragma unroll
    for (int s8 = 0; s8 < 8; ++s8) {
        const int s   = s8 * 512 + tid;
        const int c   = s >> 8;
        const int rem = s & 255;
        const int nt  = rem >> 6;
        const int ln  = rem & 63;
        const int e   = nt * 16 + (ln & 15);
        const int kb  = ks * KSEG + c * 32 + (ln >> 4) * 8;
        const f32x8 wv = *reinterpret_cast<const f32x8*>(W + (size_t)e * DIM + kb);
        short8 h, l;
#pragma unroll
        for (int j = 0; j < 8; ++j) {
            short hh, ll;
            bf16split(wv[j], hh, ll);
            h[j] = hh; l[j] = ll;
        }
        Bls[0][c][nt][ln] = h;
        Bls[1][c][nt][ln] = l;
    }
    __syncthreads();   // the only barrier in the kernel

    const float* xp = x + (size_t)(t0 + row) * DIM + ks * KSEG + grp * 8;

    f32x4 acc[4];
#pragma unroll
    for (int nt = 0; nt < 4; ++nt) acc[nt] = (f32x4){0.f, 0.f, 0.f, 0.f};

    short8 bA[8], bB[8];
    auto dsB = [&](short8 (&b)[8], int c) {      // 8 x ds_read_b128, conflict-free
#pragma unroll
        for (int nt = 0; nt < 4; ++nt) {
            b[nt]     = Bls[0][c][nt][lane];
            b[4 + nt] = Bls[1][c][nt][lane];
        }
    };
    auto ldx = [&](int c) {
        return *reinterpret_cast<const f32x8*>(xp + c * 32);
    };
    auto cvt = [&](const f32x8& xv, short8& ah, short8& al) {
#pragma unroll
        for (int j = 0; j < 8; ++j) {
            short hh, ll;
            bf16split(xv[j], hh, ll);
            ah[j] = hh; al[j] = ll;
        }
    };
    auto mfma12 = [&](const short8& ah, const short8& al, const short8 (&b)[8]) {
        // 3-pass split: hh + lh + hl (ll ~ 2^-16 relative, dropped)
        __builtin_amdgcn_s_setprio(1);
#pragma unroll
        for (int nt = 0; nt < 4; ++nt)
            acc[nt] = __builtin_amdgcn_mfma_f32_16x16x32_bf16(ah, b[nt], acc[nt], 0, 0, 0);
#pragma unroll
        for (int nt = 0; nt < 4; ++nt)
            acc[nt] = __builtin_amdgcn_mfma_f32_16x16x32_bf16(al, b[nt], acc[nt], 0, 0, 0);
#pragma unroll
        for (int nt = 0; nt < 4; ++nt)
            acc[nt] = __builtin_amdgcn_mfma_f32_16x16x32_bf16(ah, b[4 + nt], acc[nt], 0, 0, 0);
        __builtin_amdgcn_s_setprio(0);
    };

    // prologue: B(0) from LDS, x ring depth 6 in flight
    f32x8 x0 = ldx(0), x1 = ldx(1), x2 = ldx(2),
          x3 = ldx(3), x4 = ldx(4), x5 = ldx(5);
    dsB(bA, 0);
    SBAR();

    short8 ah, al;
#define PH(c, XV, BC, BN)                                            \
    {                                                                \
        cvt(XV, ah, al);          /* convert frees XV's slot */      \
        SBAR();                                                      \
        if ((c) + 1 < NCH) dsB(BN, (c) + 1);                         \
        if ((c) + 6 < NCH) XV = ldx((c) + 6);                        \
        SBAR();                                                      \
        mfma12(ah, al, BC);                                          \
        SBAR();                                                      \
    }

    PH(0,  x0, bA, bB)
    PH(1,  x1, bB, bA)
    PH(2,  x2, bA, bB)
    PH(3,  x3, bB, bA)
    PH(4,  x4, bA, bB)
    PH(5,  x5, bB, bA)
    PH(6,  x0, bA, bB)
    PH(7,  x1, bB, bA)
    PH(8,  x2, bA, bB)
    PH(9,  x3, bB, bA)
    PH(10, x4, bA, bB)
    PH(11, x5, bB, bA)
    PH(12, x0, bA, bB)
    PH(13, x1, bB, bA)
    PH(14, x2, bA, bB)
    PH(15, x3, bB, bA)
#undef PH

    // ---- direct partial write: wave owns its 16 tokens, no reduction ----
    // D layout (m89-verified): col = lane&15, row = grp*4 + reg
    float* pp = part + ((size_t)ks * TOKENS + t0) * NEXP;
#pragma unroll
    for (int nt = 0; nt < 4; ++nt)
#pragma unroll
        for (int r = 0; r < 4; ++r)
            pp[(grp * 4 + r) * NEXP + nt * 16 + row] = acc[nt][r];
}

// ---- finalize: sum 8 k-split partials, wave-per-token softmax + top-2 ----
__global__ __launch_bounds__(256)
void tg_final(const float* __restrict__ part,
              float* __restrict__ out_w, float* __restrict__ out_i) {
    const int lane = threadIdx.x & 63;
    const int wv   = threadIdx.x >> 6;
    const int t    = blockIdx.x * 4 + wv;        // one token per wave

    float s = 0.0f;
#pragma unroll
    for (int k = 0; k < KS; ++k)                 // coalesced 256-B reads
        s += part[((size_t)k * TOKENS + t) * NEXP + lane];

    // softmax over 64 lanes (butterfly: all lanes converge bit-identically)
    float m = s;
#pragma unroll
    for (int o = 32; o > 0; o >>= 1) m = fmaxf(m, __shfl_xor(m, o));
    float p = expf(s - m);
    float sum = p;
#pragma unroll
    for (int o = 32; o > 0; o >>= 1) sum += __shfl_xor(sum, o);
    const float prob = p / sum;

    // top-1: max value, tie -> lower index (jax top_k order)
    float v1 = prob; int i1 = lane;
#pragma unroll
    for (int o = 32; o > 0; o >>= 1) {
        float ov = __shfl_xor(v1, o); int oi = __shfl_xor(i1, o);
        if (ov > v1 || (ov == v1 && oi < i1)) { v1 = ov; i1 = oi; }
    }
    // top-2: mask winner (probs >= 0 > -1)
    float v2 = (lane == i1) ? -1.0f : prob; int i2 = lane;
#pragma unroll
    for (int o = 32; o > 0; o >>= 1) {
        float ov = __shfl_xor(v2, o); int oi = __shfl_xor(i2, o);
        if (ov > v2 || (ov == v2 && oi < i2)) { v2 = ov; i2 = oi; }
    }

    out_w[(size_t)t * NEXP + lane] = (lane == i1) ? v1 : (lane == i2) ? v2 : 0.0f;
    if (lane == 0) {
        out_i[(size_t)t * 2 + 0] = (float)i1;
        out_i[(size_t)t * 2 + 1] = (float)i2;
    }
}

extern "C" void kernel_launch(void* const* d_in, const int* in_sizes, int n_in,
                              void* d_out, int out_size, void* d_ws, size_t ws_size,
                              hipStream_t stream) {
    const float* x = (const float*)d_in[0];
    const float* W = (const float*)d_in[1];
    float* out_w = (float*)d_out;
    float* out_i = out_w + (size_t)TOKENS * NEXP;

    float* part = (float*)d_ws;   // KS * 8192 * 64 f32 = 16 MB

    tg_mfma <<<dim3((TOKENS / 128) * KS), dim3(512), 0, stream>>>(x, W, part);
    tg_final<<<dim3(TOKENS / 4), dim3(256), 0, stream>>>(part, out_w, out_i);
}